// Round 11
// baseline (889.941 us; speedup 1.0000x reference)
//
#include <hip/hip_runtime.h>
#include <math.h>

#define D 128
#define HQ 4        // node quarters
#define NBLK 512    // grid: 2 blocks/CU (capacity 3) -> co-residency guaranteed
#define BB 64       // scan chunks per (g,h): 2*HQ*BB == NBLK

// ---------------------------------------------------------------------------
// Collapsed linear GCN (math unchanged, absmax 0.0 since R0):
//   u0 = 1/N,  u_{k+1}[s] = sum_{e: src_e=s} inv_deg[dst_e] * u_k[dst_e]
//   mean(h3) = r@W0W1W2 + s2*(b0@W1W2) + s1*(b1@W2) + b2,  r = u3^T feat
// R2-R8: LDS histograms, 16-wide ILP scans, 4-slice reduces, split-K final.
// R9 FAILED: hipLaunchCooperativeKernel never executed (launch rejected,
// error unchecked). R10: same fusion, regular launch + manual grid barrier
// (device-scope atomics + threadfence per G16); 512 blocks @ 2/CU leaves a
// full block/CU of co-residency margin. Barrier counters zeroed by a tiny
// hipMemsetAsync before the kernel (captured in the graph).
// ---------------------------------------------------------------------------

struct Params {
    const float* feat_p; const int* src_p; const int* dst_p;
    const float* feat_s; const int* src_s; const int* dst_s;
    const float *W0, *b0, *W1, *b1, *W2, *b2;
    const float *Wr, *br, *Wm1, *bm1, *Wm2, *bm2;
    float* out;
    int*   bar;     // [32] barrier counters (pre-zeroed)
    float* sums;    // [16]
    float* inv;     // [2N]
    float* w1;      // [2N]
    float* w2;      // [2N]
    float* u3;      // [2N]
    float* fpart;   // [2*NBg*128]
    float* fpart2;  // [2*16*128]
    float* rep;     // [2*HQ*BB*HN]
    int N, E, HN, NBg;
    float u0;
};

__device__ __forceinline__ void gsync(int* bar, int idx) {
    __syncthreads();
    if (threadIdx.x == 0) {
        __threadfence();                       // release: drain + L2 writeback
        atomicAdd(&bar[idx], 1);               // device-scope by default
        while (__hip_atomic_load(&bar[idx], __ATOMIC_RELAXED,
                                 __HIP_MEMORY_SCOPE_AGENT) < NBLK)
            __builtin_amdgcn_s_sleep(2);
        __threadfence();                       // acquire: invalidate caches
    }
    __syncthreads();
}

// ---- scan: rep[g][h][b][HN] partials via LDS histogram -------------------
__device__ __forceinline__ void scan_phase(
        const Params& p, float* lds,
        const int* tgt_p, const int* oth_p,
        const int* tgt_s, const int* oth_s,
        const float* w, float scale) {
    const int HN = p.HN, N = p.N, E = p.E;
    const int id = blockIdx.x;
    const int b = id % BB;
    const int h = (id / BB) % HQ;
    const int g = id / (HQ * BB);
    const int* tgt = g ? tgt_s : tgt_p;
    const int* oth = g ? oth_s : oth_p;
    const float* wg = w ? (w + (size_t)g * N) : nullptr;

    {
        float4 z = make_float4(0.f, 0.f, 0.f, 0.f);
        float4* l4 = (float4*)lds;
        for (int i = threadIdx.x; i < HN / 4; i += 512) l4[i] = z;
    }
    __syncthreads();

    const int lo = h * HN;
    const int hi = min(lo + HN, N);
    const unsigned span = (unsigned)(hi - lo);
    int C = (E + BB - 1) / BB;
    C = (C + 15) & ~15;
    const int e0 = b * C;
    const int e1 = min(e0 + C, E);

    for (int e = e0 + (int)threadIdx.x * 16; e < e1; e += 512 * 16) {
        if (e + 16 <= e1) {
            int idx[16];
            #pragma unroll
            for (int q = 0; q < 4; ++q) {
                int4 t4 = *(const int4*)(tgt + e + 4 * q);
                idx[4 * q + 0] = t4.x; idx[4 * q + 1] = t4.y;
                idx[4 * q + 2] = t4.z; idx[4 * q + 3] = t4.w;
            }
            bool hit[16];
            #pragma unroll
            for (int k = 0; k < 16; ++k) hit[k] = (unsigned)(idx[k] - lo) < span;
            if (wg) {
                int od[16];
                #pragma unroll
                for (int q = 0; q < 4; ++q) {
                    int4 o4 = *(const int4*)(oth + e + 4 * q);
                    od[4 * q + 0] = o4.x; od[4 * q + 1] = o4.y;
                    od[4 * q + 2] = o4.z; od[4 * q + 3] = o4.w;
                }
                float val[16];
                #pragma unroll
                for (int k = 0; k < 16; ++k) val[k] = hit[k] ? wg[od[k]] : 0.f;
                #pragma unroll
                for (int k = 0; k < 16; ++k)
                    if (hit[k]) atomicAdd(&lds[idx[k] - lo], val[k] * scale);
            } else {
                #pragma unroll
                for (int k = 0; k < 16; ++k)
                    if (hit[k]) atomicAdd(&lds[idx[k] - lo], 1.0f);
            }
        } else {
            for (int e2 = e; e2 < e1; ++e2) {
                int t = tgt[e2];
                if ((unsigned)(t - lo) < span) {
                    float v = wg ? wg[oth[e2]] * scale : 1.0f;
                    atomicAdd(&lds[t - lo], v);
                }
            }
        }
    }
    __syncthreads();

    float* dst = p.rep + (((size_t)g * HQ + h) * BB + b) * HN;
    float4* d4 = (float4*)dst;
    const float4* l4 = (const float4*)lds;
    for (int i = threadIdx.x; i < HN / 4; i += 512) d4[i] = l4[i];
}

// ---- reduce: sum over BB partials. mode 0 -> inv; mode 1 -> u (+opts) ----
__device__ __forceinline__ void reduce_phase(
        const Params& p, float* lds, int mode, int s_idx,
        float* out_u, float* out_w) {
    const int N = p.N, HN = p.HN;
    const int lane = threadIdx.x & 127;
    const int s = threadIdx.x >> 7;           // 0..3
    const int i = (blockIdx.x * 128 + lane) * 4;
    const int bps = BB >> 2;                  // 16
    float4 u = make_float4(0.f, 0.f, 0.f, 0.f);
    if (i < 2 * N) {
        int g = (i < N) ? 0 : 1;
        int n = i - g * N;
        int h = n / HN, l = n - h * HN;
        const float* base = p.rep + (((size_t)g * HQ + h) * BB + (size_t)s * bps) * HN + l;
        #pragma unroll 16
        for (int b = 0; b < bps; b++) {
            float4 v = *(const float4*)(base + (size_t)b * HN);
            u.x += v.x; u.y += v.y; u.z += v.z; u.w += v.w;
        }
    }
    float4* sm = (float4*)lds;                // 512 float4 = 8 KB
    float* s0 = lds + 2048;                   // 128
    float* s1 = lds + 2176;                   // 128
    sm[threadIdx.x] = u;
    __syncthreads();
    if (s == 0) {
        float tp = 0.f, ts = 0.f;
        if (i < 2 * N) {
            float4 a = sm[lane], b4 = sm[128 + lane], c = sm[256 + lane], d = sm[384 + lane];
            float4 uu;
            uu.x = a.x + b4.x + c.x + d.x;
            uu.y = a.y + b4.y + c.y + d.y;
            uu.z = a.z + b4.z + c.z + d.z;
            uu.w = a.w + b4.w + c.w + d.w;
            if (mode == 0) {
                float4 r;
                r.x = 1.0f / fmaxf(uu.x, 1.0f); r.y = 1.0f / fmaxf(uu.y, 1.0f);
                r.z = 1.0f / fmaxf(uu.z, 1.0f); r.w = 1.0f / fmaxf(uu.w, 1.0f);
                *(float4*)(p.inv + i) = r;
            } else {
                if (out_u) *(float4*)(out_u + i) = uu;
                if (out_w) {
                    float4 iv = *(const float4*)(p.inv + i);
                    *(float4*)(out_w + i) =
                        make_float4(uu.x * iv.x, uu.y * iv.y, uu.z * iv.z, uu.w * iv.w);
                }
                float t = uu.x + uu.y + uu.z + uu.w;
                if (i < N) tp = t; else ts = t;
            }
        }
        s0[lane] = tp; s1[lane] = ts;
    }
    __syncthreads();
    if (mode == 1 && s_idx >= 0) {
        for (int st = 64; st > 0; st >>= 1) {
            if ((int)threadIdx.x < st) {
                s0[threadIdx.x] += s0[threadIdx.x + st];
                s1[threadIdx.x] += s1[threadIdx.x + st];
            }
            __syncthreads();
        }
        if (threadIdx.x == 0) {
            if (s0[0] != 0.f) atomicAdd(&p.sums[0 * 2 + s_idx], s0[0]);
            if (s1[0] != 0.f) atomicAdd(&p.sums[1 * 2 + s_idx], s1[0]);
        }
    }
}

// ---- featsum: fpart[(g*NBg+bg)][c] = partial u3^T feat ------------------
__device__ __forceinline__ void featsum_phase(const Params& p, float* lds) {
    const int NBg = p.NBg;                    // 256; 2*NBg == NBLK
    const int id = blockIdx.x;
    const int g = id / NBg;
    const int bg = id - g * NBg;
    const float* feat = g ? p.feat_s : p.feat_p;
    const float* u = p.u3 + (size_t)g * p.N;
    const int rpb = ((p.N + NBg - 1) / NBg + 3) & ~3;
    const int r0 = bg * rpb;
    const int r1 = min(r0 + rpb, p.N);
    const int col4 = threadIdx.x & 31;
    const int rg = threadIdx.x >> 5;          // 0..15

    const float4* f4 = (const float4*)feat;
    float4 acc = make_float4(0.f, 0.f, 0.f, 0.f);
    for (int n = r0 + rg * 4; n + 3 < r1; n += 64) {
        float4 uu = *(const float4*)(u + n);
        float4 v0 = f4[(size_t)n * 32 + col4];
        float4 v1 = f4[(size_t)(n + 1) * 32 + col4];
        float4 v2 = f4[(size_t)(n + 2) * 32 + col4];
        float4 v3 = f4[(size_t)(n + 3) * 32 + col4];
        acc.x += uu.x * v0.x + uu.y * v1.x + uu.z * v2.x + uu.w * v3.x;
        acc.y += uu.x * v0.y + uu.y * v1.y + uu.z * v2.y + uu.w * v3.y;
        acc.z += uu.x * v0.z + uu.y * v1.z + uu.z * v2.z + uu.w * v3.z;
        acc.w += uu.x * v0.w + uu.y * v1.w + uu.z * v2.w + uu.w * v3.w;
    }
    float4* smem = (float4*)lds;
    smem[threadIdx.x] = acc;
    __syncthreads();
    if (rg == 0) {
        float4 t = smem[col4];
        #pragma unroll
        for (int k = 1; k < 16; k++) {
            float4 o = smem[k * 32 + col4];
            t.x += o.x; t.y += o.y; t.z += o.z; t.w += o.w;
        }
        float4* dst = (float4*)(p.fpart + ((size_t)g * NBg + bg) * 128);
        dst[col4] = t;
    }
}

// ---- fpart pre-reduce: [2][NBg][128] -> [2][16][128] (blocks 0..31) -----
__device__ __forceinline__ void fpart2_phase(const Params& p, float* lds) {
    if (blockIdx.x >= 32) return;
    const int g = blockIdx.x >> 4, b = blockIdx.x & 15;
    const int per = p.NBg / 16;               // 16
    const int sl = per / 4;                   // 4
    const int j = threadIdx.x & 127, seg = threadIdx.x >> 7;
    const float* fp = p.fpart + ((size_t)(g * p.NBg + b * per + seg * sl)) * 128 + j;
    float s = 0.f;
    #pragma unroll 4
    for (int k = 0; k < sl; ++k) s += fp[(size_t)k * 128];
    lds[seg * 128 + j] = s;
    __syncthreads();
    if (seg == 0)
        p.fpart2[((size_t)g * 16 + b) * 128 + j] =
            lds[j] + lds[128 + j] + lds[256 + j] + lds[384 + j];
}

// ---- final: split-K matvec chain (block 0) ------------------------------
__device__ __forceinline__ void final_phase(const Params& p, float* lds) {
    float* x    = lds;            // 128
    float* part = lds + 128;      // 4*128
    float* rvec = lds + 640;      // 256
    float* Avec = lds + 896;      // 128
    float* Bvec = lds + 1024;     // 128
    float* gv   = lds + 1152;     // 256
    const int tid = threadIdx.x;
    const int j = tid & 127;
    const int h = tid >> 7;

    auto mv128 = [&](const float* __restrict__ W, float* __restrict__ buf) {
        float pp = 0.f;
        const float* Wp = W + (size_t)(h * 32) * 128 + j;
        #pragma unroll
        for (int i = 0; i < 32; ++i) pp += buf[h * 32 + i] * Wp[(size_t)i * 128];
        part[h * 128 + j] = pp;
        __syncthreads();
        if (h == 0) buf[j] = part[j] + part[128 + j] + part[256 + j] + part[384 + j];
        __syncthreads();
    };

    if (tid < 256) {
        int g = tid >> 7;
        const float* fp = p.fpart2 + (size_t)g * 2048 + (tid & 127);
        float rv = 0.f;
        #pragma unroll
        for (int b = 0; b < 16; ++b) rv += fp[(size_t)b * 128];
        rvec[tid] = rv;
    }
    __syncthreads();

    if (tid < 128) x[tid] = p.b0[tid];
    __syncthreads();
    mv128(p.W1, x);
    mv128(p.W2, x);
    if (tid < 128) Avec[tid] = x[tid];
    __syncthreads();
    if (tid < 128) x[tid] = p.b1[tid];
    __syncthreads();
    mv128(p.W2, x);
    if (tid < 128) Bvec[tid] = x[tid];
    __syncthreads();

    for (int g = 0; g < 2; ++g) {
        const float s1 = p.sums[g * 2 + 0];
        const float s2 = p.sums[g * 2 + 1];
        if (tid < 128) x[tid] = rvec[g * 128 + tid];
        __syncthreads();
        mv128(p.W0, x);
        mv128(p.W1, x);
        mv128(p.W2, x);
        if (tid < 128) x[tid] += s2 * Avec[tid] + s1 * Bvec[tid] + p.b2[tid];
        __syncthreads();
        mv128(p.Wr, x);
        if (tid < 128) gv[g * 128 + tid] = 1.0f / (1.0f + expf(-(x[tid] + p.br[tid])));
        __syncthreads();
    }

    {
        float pp = 0.f;
        const float* Wp = p.Wm1 + (size_t)(h * 64) * 128 + j;
        #pragma unroll
        for (int i = 0; i < 64; ++i) pp += gv[h * 64 + i] * Wp[(size_t)i * 128];
        part[h * 128 + j] = pp;
        __syncthreads();
        if (h == 0)
            part[j] = (part[j] + part[128 + j] + part[256 + j] + part[384 + j] + p.bm1[j]) * p.Wm2[j];
        __syncthreads();
        for (int st = 64; st > 1; st >>= 1) {
            if (tid < st) part[tid] += part[tid + st];
            __syncthreads();
        }
        if (tid == 0)
            p.out[0] = 1.0f / (1.0f + expf(-(part[0] + part[1] + p.bm2[0])));
    }
}

__global__ __launch_bounds__(512, 4) void fused_kernel(Params p) {
    extern __shared__ float lds[];
    int* bar = p.bar;

    // P0: degree
    scan_phase(p, lds, p.dst_p, nullptr, p.dst_s, nullptr, nullptr, 1.0f);
    gsync(bar, 0);
    reduce_phase(p, lds, 0, -1, nullptr, nullptr);                 // inv
    gsync(bar, 1);
    // P1: u1
    scan_phase(p, lds, p.src_p, p.dst_p, p.src_s, p.dst_s, p.inv, p.u0);
    gsync(bar, 2);
    reduce_phase(p, lds, 1, 0, nullptr, p.w1);                     // w1, s1
    gsync(bar, 3);
    // P2: u2
    scan_phase(p, lds, p.src_p, p.dst_p, p.src_s, p.dst_s, p.w1, 1.0f);
    gsync(bar, 4);
    reduce_phase(p, lds, 1, 1, nullptr, p.w2);                     // w2, s2
    gsync(bar, 5);
    // P3: u3
    scan_phase(p, lds, p.src_p, p.dst_p, p.src_s, p.dst_s, p.w2, 1.0f);
    gsync(bar, 6);
    reduce_phase(p, lds, 1, -1, p.u3, nullptr);                    // u3
    gsync(bar, 7);
    // P4: featsum
    featsum_phase(p, lds);
    gsync(bar, 8);
    fpart2_phase(p, lds);
    gsync(bar, 9);
    if (blockIdx.x == 0) final_phase(p, lds);
}

extern "C" void kernel_launch(void* const* d_in, const int* in_sizes, int n_in,
                              void* d_out, int out_size, void* d_ws, size_t ws_size,
                              hipStream_t stream) {
    const int N = in_sizes[0] / D;   // 50000
    const int E = in_sizes[1];       // 1600000
    const int N2 = 2 * N;

    int HN = (N + HQ - 1) / HQ;
    HN = (HN + 3) & ~3;              // 12500
    const int NBg = NBLK / 2;        // 256 featsum blocks per graph

    // ws (floats): bar[32 ints] | sums[16] | inv[2N] | w1[2N] | w2[2N] | u3[2N]
    //              | fpart[2*NBg*128] | fpart2[2*16*128] | rep[2*HQ*BB*HN]
    float* ws     = (float*)d_ws;
    int*   bar    = (int*)ws;
    float* sums   = ws + 32;
    float* inv    = ws + 48;
    float* w1     = inv + N2;
    float* w2     = w1 + N2;
    float* u3     = w2 + N2;
    float* fpart  = u3 + N2;
    float* fpart2 = fpart + (size_t)2 * NBg * 128;
    float* rep    = fpart2 + 2 * 16 * 128;

    // zero barrier counters + sums (192 B)
    hipMemsetAsync(d_ws, 0, 48 * sizeof(float), stream);

    Params p;
    p.feat_p = (const float*)d_in[0];
    p.src_p  = (const int*)d_in[1];
    p.dst_p  = (const int*)d_in[2];
    p.feat_s = (const float*)d_in[3];
    p.src_s  = (const int*)d_in[4];
    p.dst_s  = (const int*)d_in[5];
    p.W0 = (const float*)d_in[6];  p.b0 = (const float*)d_in[7];
    p.W1 = (const float*)d_in[8];  p.b1 = (const float*)d_in[9];
    p.W2 = (const float*)d_in[10]; p.b2 = (const float*)d_in[11];
    p.Wr = (const float*)d_in[12]; p.br = (const float*)d_in[13];
    p.Wm1 = (const float*)d_in[14]; p.bm1 = (const float*)d_in[15];
    p.Wm2 = (const float*)d_in[16]; p.bm2 = (const float*)d_in[17];
    p.out = (float*)d_out;
    p.bar = bar; p.sums = sums; p.inv = inv; p.w1 = w1; p.w2 = w2; p.u3 = u3;
    p.fpart = fpart; p.fpart2 = fpart2; p.rep = rep;
    p.N = N; p.E = E; p.HN = HN; p.NBg = NBg;
    p.u0 = 1.0f / (float)N;

    const unsigned lds_bytes = (unsigned)(HN * sizeof(float));  // 50 KB
    fused_kernel<<<NBLK, 512, lds_bytes, stream>>>(p);
}

// Round 12
// 841.759 us; speedup vs baseline: 1.0572x; 1.0572x over previous
//
#include <hip/hip_runtime.h>
#include <math.h>

#define D 128
#define HQ 4        // node quarters
#define NBLK 768    // 3 blocks/CU (exact LDS capacity) -> all co-resident
#define BB 96       // scan chunks per (g,h): 2*HQ*BB == NBLK

// ---------------------------------------------------------------------------
// Collapsed linear GCN (math unchanged, absmax 0.0 since R0):
//   u0 = 1/N,  u_{k+1}[s] = sum_{e: src_e=s} inv_deg[dst_e] * u_k[dst_e]
//   mean(h3) = r@W0W1W2 + s2*(b0@W1W2) + s1*(b1@W2) + b2,  r = u3^T feat
// R10: fused w/ __threadfence barriers = 808us. Fences emit buffer_wbl2 /
// buffer_inv (full L2 sweeps) x 512 blocks x 10 barriers, and the invalidate
// killed edge/w caching between phases.
// R11: FENCE-FREE barriers. All cross-phase mutable data moves via
// agent-scope (L2-bypassing) loads/stores, so no writeback/invalidate is
// needed; barrier = syncthreads + relaxed device atomicAdd + relaxed poll.
// Read-only + write-once-then-read data stays normally cached (first touch
// is always after the write; kernel boundaries invalidate L2 across replays).
// ---------------------------------------------------------------------------

typedef unsigned long long u64;

__device__ __forceinline__ void cstore4(float* p, float4 v) {
    u64 lo, hi;
    __builtin_memcpy(&lo, &v.x, 8);
    __builtin_memcpy(&hi, &v.z, 8);
    __hip_atomic_store((u64*)p, lo, __ATOMIC_RELAXED, __HIP_MEMORY_SCOPE_AGENT);
    __hip_atomic_store((u64*)p + 1, hi, __ATOMIC_RELAXED, __HIP_MEMORY_SCOPE_AGENT);
}
__device__ __forceinline__ float4 cload4(const float* p) {
    u64 lo = __hip_atomic_load((const u64*)p, __ATOMIC_RELAXED, __HIP_MEMORY_SCOPE_AGENT);
    u64 hi = __hip_atomic_load((const u64*)p + 1, __ATOMIC_RELAXED, __HIP_MEMORY_SCOPE_AGENT);
    float4 v;
    __builtin_memcpy(&v.x, &lo, 8);
    __builtin_memcpy(&v.z, &hi, 8);
    return v;
}
__device__ __forceinline__ void cstore1(float* p, float v) {
    __hip_atomic_store(p, v, __ATOMIC_RELAXED, __HIP_MEMORY_SCOPE_AGENT);
}
__device__ __forceinline__ float cload1(const float* p) {
    return __hip_atomic_load(p, __ATOMIC_RELAXED, __HIP_MEMORY_SCOPE_AGENT);
}

struct Params {
    const float* feat_p; const int* src_p; const int* dst_p;
    const float* feat_s; const int* src_s; const int* dst_s;
    const float *W0, *b0, *W1, *b1, *W2, *b2;
    const float *Wr, *br, *Wm1, *bm1, *Wm2, *bm2;
    float* out;
    int*   bar;     // [32] barrier counters (pre-zeroed)
    float* sums;    // [16] (pre-zeroed)
    float* inv;     // [2N]
    float* w1;      // [2N]
    float* w2;      // [2N]
    float* u3;      // [2N]
    float* fpart;   // [2*NBg*128]
    float* fpart2;  // [2*16*128]
    float* rep;     // [2*HQ*BB*HN]
    int N, E, HN, NBg;
    float u0;
};

// fence-free grid barrier: writes are already at the coherence point
// (agent-scope stores); __syncthreads drains each wave's vmcnt.
__device__ __forceinline__ void gsync(int* bar, int idx) {
    __syncthreads();
    if (threadIdx.x == 0) {
        __hip_atomic_fetch_add(&bar[idx], 1, __ATOMIC_RELAXED, __HIP_MEMORY_SCOPE_AGENT);
        while (__hip_atomic_load(&bar[idx], __ATOMIC_RELAXED,
                                 __HIP_MEMORY_SCOPE_AGENT) < NBLK)
            __builtin_amdgcn_s_sleep(8);
        asm volatile("" ::: "memory");
    }
    __syncthreads();
}

// ---- scan: rep[g][h][b][HN] partials via LDS histogram -------------------
__device__ __forceinline__ void scan_phase(
        const Params& p, float* lds,
        const int* tgt_p, const int* oth_p,
        const int* tgt_s, const int* oth_s,
        const float* w, float scale) {
    const int HN = p.HN, N = p.N, E = p.E;
    const int id = blockIdx.x;
    const int b = id % BB;
    const int h = (id / BB) % HQ;
    const int g = id / (HQ * BB);
    const int* tgt = g ? tgt_s : tgt_p;
    const int* oth = g ? oth_s : oth_p;
    const float* wg = w ? (w + (size_t)g * N) : nullptr;

    {
        float4 z = make_float4(0.f, 0.f, 0.f, 0.f);
        float4* l4 = (float4*)lds;
        for (int i = threadIdx.x; i < HN / 4; i += 512) l4[i] = z;
    }
    __syncthreads();

    const int lo = h * HN;
    const int hi = min(lo + HN, N);
    const unsigned span = (unsigned)(hi - lo);
    int C = (E + BB - 1) / BB;
    C = (C + 15) & ~15;
    const int e0 = b * C;
    const int e1 = min(e0 + C, E);

    for (int e = e0 + (int)threadIdx.x * 16; e < e1; e += 512 * 16) {
        if (e + 16 <= e1) {
            int idx[16];
            #pragma unroll
            for (int q = 0; q < 4; ++q) {
                int4 t4 = *(const int4*)(tgt + e + 4 * q);
                idx[4 * q + 0] = t4.x; idx[4 * q + 1] = t4.y;
                idx[4 * q + 2] = t4.z; idx[4 * q + 3] = t4.w;
            }
            bool hit[16];
            #pragma unroll
            for (int k = 0; k < 16; ++k) hit[k] = (unsigned)(idx[k] - lo) < span;
            if (wg) {
                int od[16];
                #pragma unroll
                for (int q = 0; q < 4; ++q) {
                    int4 o4 = *(const int4*)(oth + e + 4 * q);
                    od[4 * q + 0] = o4.x; od[4 * q + 1] = o4.y;
                    od[4 * q + 2] = o4.z; od[4 * q + 3] = o4.w;
                }
                float val[16];
                #pragma unroll
                for (int k = 0; k < 16; ++k) val[k] = hit[k] ? wg[od[k]] : 0.f;
                #pragma unroll
                for (int k = 0; k < 16; ++k)
                    if (hit[k]) atomicAdd(&lds[idx[k] - lo], val[k] * scale);
            } else {
                #pragma unroll
                for (int k = 0; k < 16; ++k)
                    if (hit[k]) atomicAdd(&lds[idx[k] - lo], 1.0f);
            }
        } else {
            for (int e2 = e; e2 < e1; ++e2) {
                int t = tgt[e2];
                if ((unsigned)(t - lo) < span) {
                    float v = wg ? wg[oth[e2]] * scale : 1.0f;
                    atomicAdd(&lds[t - lo], v);
                }
            }
        }
    }
    __syncthreads();

    float* dst = p.rep + (((size_t)g * HQ + h) * BB + b) * HN;
    const float4* l4 = (const float4*)lds;
    for (int i = threadIdx.x; i < HN / 4; i += 512) cstore4(dst + 4 * i, l4[i]);
}

// ---- reduce: sum over BB partials. mode 0 -> inv; mode 1 -> u (+opts) ----
__device__ __forceinline__ void reduce_phase(
        const Params& p, float* lds, int mode, int s_idx,
        float* out_u, float* out_w) {
    const int N = p.N, HN = p.HN;
    const int lane = threadIdx.x & 127;
    const int s = threadIdx.x >> 7;           // 0..3
    const int i = (blockIdx.x * 128 + lane) * 4;
    const int bps = BB >> 2;                  // 24
    float4 u = make_float4(0.f, 0.f, 0.f, 0.f);
    if (i < 2 * N) {
        int g = (i < N) ? 0 : 1;
        int n = i - g * N;
        int h = n / HN, l = n - h * HN;
        const float* base = p.rep + (((size_t)g * HQ + h) * BB + (size_t)s * bps) * HN + l;
        #pragma unroll 24
        for (int b = 0; b < bps; b++) {
            float4 v = cload4(base + (size_t)b * HN);
            u.x += v.x; u.y += v.y; u.z += v.z; u.w += v.w;
        }
    }
    float4* sm = (float4*)lds;                // 512 float4 = 8 KB
    float* s0 = lds + 2048;                   // 128
    float* s1 = lds + 2176;                   // 128
    sm[threadIdx.x] = u;
    __syncthreads();
    if (s == 0) {
        float tp = 0.f, ts = 0.f;
        if (i < 2 * N) {
            float4 a = sm[lane], b4 = sm[128 + lane], c = sm[256 + lane], d = sm[384 + lane];
            float4 uu;
            uu.x = a.x + b4.x + c.x + d.x;
            uu.y = a.y + b4.y + c.y + d.y;
            uu.z = a.z + b4.z + c.z + d.z;
            uu.w = a.w + b4.w + c.w + d.w;
            if (mode == 0) {
                float4 r;
                r.x = 1.0f / fmaxf(uu.x, 1.0f); r.y = 1.0f / fmaxf(uu.y, 1.0f);
                r.z = 1.0f / fmaxf(uu.z, 1.0f); r.w = 1.0f / fmaxf(uu.w, 1.0f);
                cstore4(p.inv + i, r);
            } else {
                if (out_u) cstore4(out_u + i, uu);
                if (out_w) {
                    float4 iv = *(const float4*)(p.inv + i);  // write-once, cached ok
                    cstore4(out_w + i,
                            make_float4(uu.x * iv.x, uu.y * iv.y, uu.z * iv.z, uu.w * iv.w));
                }
                float t = uu.x + uu.y + uu.z + uu.w;
                if (i < N) tp = t; else ts = t;
            }
        }
        s0[lane] = tp; s1[lane] = ts;
    }
    __syncthreads();
    if (mode == 1 && s_idx >= 0) {
        for (int st = 64; st > 0; st >>= 1) {
            if ((int)threadIdx.x < st) {
                s0[threadIdx.x] += s0[threadIdx.x + st];
                s1[threadIdx.x] += s1[threadIdx.x + st];
            }
            __syncthreads();
        }
        if (threadIdx.x == 0) {
            if (s0[0] != 0.f) atomicAdd(&p.sums[0 * 2 + s_idx], s0[0]);
            if (s1[0] != 0.f) atomicAdd(&p.sums[1 * 2 + s_idx], s1[0]);
        }
    }
}

// ---- featsum: fpart[(g*NBg+bg)][c] = partial u3^T feat ------------------
__device__ __forceinline__ void featsum_phase(const Params& p, float* lds) {
    const int NBg = p.NBg;                    // 384; 2*NBg == NBLK
    const int id = blockIdx.x;
    const int g = id / NBg;
    const int bg = id - g * NBg;
    const float* feat = g ? p.feat_s : p.feat_p;
    const float* u = p.u3 + (size_t)g * p.N;  // write-once (red3), cached ok
    const int rpb = ((p.N + NBg - 1) / NBg + 3) & ~3;
    const int r0 = bg * rpb;
    const int r1 = min(r0 + rpb, p.N);
    const int col4 = threadIdx.x & 31;
    const int rg = threadIdx.x >> 5;          // 0..15

    const float4* f4 = (const float4*)feat;
    float4 acc = make_float4(0.f, 0.f, 0.f, 0.f);
    for (int n = r0 + rg * 4; n + 3 < r1; n += 64) {
        float4 uu = *(const float4*)(u + n);
        float4 v0 = f4[(size_t)n * 32 + col4];
        float4 v1 = f4[(size_t)(n + 1) * 32 + col4];
        float4 v2 = f4[(size_t)(n + 2) * 32 + col4];
        float4 v3 = f4[(size_t)(n + 3) * 32 + col4];
        acc.x += uu.x * v0.x + uu.y * v1.x + uu.z * v2.x + uu.w * v3.x;
        acc.y += uu.x * v0.y + uu.y * v1.y + uu.z * v2.y + uu.w * v3.y;
        acc.z += uu.x * v0.z + uu.y * v1.z + uu.z * v2.z + uu.w * v3.z;
        acc.w += uu.x * v0.w + uu.y * v1.w + uu.z * v2.w + uu.w * v3.w;
    }
    float4* smem = (float4*)lds;
    smem[threadIdx.x] = acc;
    __syncthreads();
    if (rg == 0) {
        float4 t = smem[col4];
        #pragma unroll
        for (int k = 1; k < 16; k++) {
            float4 o = smem[k * 32 + col4];
            t.x += o.x; t.y += o.y; t.z += o.z; t.w += o.w;
        }
        cstore4(p.fpart + ((size_t)g * NBg + bg) * 128 + col4 * 4, t);
    }
}

// ---- fpart pre-reduce: [2][NBg][128] -> [2][16][128] (blocks 0..31) -----
__device__ __forceinline__ void fpart2_phase(const Params& p, float* lds) {
    if (blockIdx.x >= 32) return;
    const int g = blockIdx.x >> 4, b = blockIdx.x & 15;
    const int per = p.NBg / 16;               // 24
    const int sl = per / 4;                   // 6
    const int j = threadIdx.x & 127, seg = threadIdx.x >> 7;
    const float* fp = p.fpart + ((size_t)(g * p.NBg + b * per + seg * sl)) * 128 + j;
    float s = 0.f;
    #pragma unroll 6
    for (int k = 0; k < sl; ++k) s += cload1(fp + (size_t)k * 128);
    lds[seg * 128 + j] = s;
    __syncthreads();
    if (seg == 0)
        cstore1(p.fpart2 + ((size_t)g * 16 + b) * 128 + j,
                lds[j] + lds[128 + j] + lds[256 + j] + lds[384 + j]);
}

// ---- final: split-K matvec chain (block 0) ------------------------------
__device__ __forceinline__ void final_phase(const Params& p, float* lds) {
    float* x    = lds;            // 128
    float* part = lds + 128;      // 4*128
    float* rvec = lds + 640;      // 256
    float* Avec = lds + 896;      // 128
    float* Bvec = lds + 1024;     // 128
    float* gv   = lds + 1152;     // 256
    const int tid = threadIdx.x;
    const int j = tid & 127;
    const int h = tid >> 7;

    auto mv128 = [&](const float* __restrict__ W, float* __restrict__ buf) {
        float pp = 0.f;
        const float* Wp = W + (size_t)(h * 32) * 128 + j;
        #pragma unroll
        for (int i = 0; i < 32; ++i) pp += buf[h * 32 + i] * Wp[(size_t)i * 128];
        part[h * 128 + j] = pp;
        __syncthreads();
        if (h == 0) buf[j] = part[j] + part[128 + j] + part[256 + j] + part[384 + j];
        __syncthreads();
    };

    if (tid < 256) {
        int g = tid >> 7;
        const float* fp = p.fpart2 + (size_t)g * 2048 + (tid & 127);
        float rv = 0.f;
        #pragma unroll
        for (int b = 0; b < 16; ++b) rv += cload1(fp + (size_t)b * 128);
        rvec[tid] = rv;
    }
    __syncthreads();

    if (tid < 128) x[tid] = p.b0[tid];
    __syncthreads();
    mv128(p.W1, x);
    mv128(p.W2, x);
    if (tid < 128) Avec[tid] = x[tid];
    __syncthreads();
    if (tid < 128) x[tid] = p.b1[tid];
    __syncthreads();
    mv128(p.W2, x);
    if (tid < 128) Bvec[tid] = x[tid];
    __syncthreads();

    for (int g = 0; g < 2; ++g) {
        const float s1 = cload1(&p.sums[g * 2 + 0]);
        const float s2 = cload1(&p.sums[g * 2 + 1]);
        if (tid < 128) x[tid] = rvec[g * 128 + tid];
        __syncthreads();
        mv128(p.W0, x);
        mv128(p.W1, x);
        mv128(p.W2, x);
        if (tid < 128) x[tid] += s2 * Avec[tid] + s1 * Bvec[tid] + p.b2[tid];
        __syncthreads();
        mv128(p.Wr, x);
        if (tid < 128) gv[g * 128 + tid] = 1.0f / (1.0f + expf(-(x[tid] + p.br[tid])));
        __syncthreads();
    }

    {
        float pp = 0.f;
        const float* Wp = p.Wm1 + (size_t)(h * 64) * 128 + j;
        #pragma unroll
        for (int i = 0; i < 64; ++i) pp += gv[h * 64 + i] * Wp[(size_t)i * 128];
        part[h * 128 + j] = pp;
        __syncthreads();
        if (h == 0)
            part[j] = (part[j] + part[128 + j] + part[256 + j] + part[384 + j] + p.bm1[j]) * p.Wm2[j];
        __syncthreads();
        for (int st = 64; st > 1; st >>= 1) {
            if (tid < st) part[tid] += part[tid + st];
            __syncthreads();
        }
        if (tid == 0)
            p.out[0] = 1.0f / (1.0f + expf(-(part[0] + part[1] + p.bm2[0])));
    }
}

__global__ __launch_bounds__(512, 6) void fused_kernel(Params p) {
    extern __shared__ float lds[];
    int* bar = p.bar;

    // P0: degree
    scan_phase(p, lds, p.dst_p, nullptr, p.dst_s, nullptr, nullptr, 1.0f);
    gsync(bar, 0);
    reduce_phase(p, lds, 0, -1, nullptr, nullptr);                 // inv
    gsync(bar, 1);
    // P1: u1
    scan_phase(p, lds, p.src_p, p.dst_p, p.src_s, p.dst_s, p.inv, p.u0);
    gsync(bar, 2);
    reduce_phase(p, lds, 1, 0, nullptr, p.w1);                     // w1, s1
    gsync(bar, 3);
    // P2: u2
    scan_phase(p, lds, p.src_p, p.dst_p, p.src_s, p.dst_s, p.w1, 1.0f);
    gsync(bar, 4);
    reduce_phase(p, lds, 1, 1, nullptr, p.w2);                     // w2, s2
    gsync(bar, 5);
    // P3: u3
    scan_phase(p, lds, p.src_p, p.dst_p, p.src_s, p.dst_s, p.w2, 1.0f);
    gsync(bar, 6);
    reduce_phase(p, lds, 1, -1, p.u3, nullptr);                    // u3
    gsync(bar, 7);
    // P4: featsum
    featsum_phase(p, lds);
    gsync(bar, 8);
    fpart2_phase(p, lds);
    gsync(bar, 9);
    if (blockIdx.x == 0) final_phase(p, lds);
}

extern "C" void kernel_launch(void* const* d_in, const int* in_sizes, int n_in,
                              void* d_out, int out_size, void* d_ws, size_t ws_size,
                              hipStream_t stream) {
    const int N = in_sizes[0] / D;   // 50000
    const int E = in_sizes[1];       // 1600000
    const int N2 = 2 * N;

    int HN = (N + HQ - 1) / HQ;
    HN = (HN + 3) & ~3;              // 12500
    const int NBg = NBLK / 2;        // 384 featsum blocks per graph

    // ws (floats): bar[32 ints] | sums[16] | inv[2N] | w1[2N] | w2[2N] | u3[2N]
    //              | fpart[2*NBg*128] | fpart2[2*16*128] | rep[2*HQ*BB*HN]
    float* ws     = (float*)d_ws;
    int*   bar    = (int*)ws;
    float* sums   = ws + 32;
    float* inv    = ws + 48;
    float* w1     = inv + N2;
    float* w2     = w1 + N2;
    float* u3     = w2 + N2;
    float* fpart  = u3 + N2;
    float* fpart2 = fpart + (size_t)2 * NBg * 128;
    float* rep    = fpart2 + 2 * 16 * 128;

    // zero barrier counters + sums (192 B)
    hipMemsetAsync(d_ws, 0, 48 * sizeof(float), stream);

    Params p;
    p.feat_p = (const float*)d_in[0];
    p.src_p  = (const int*)d_in[1];
    p.dst_p  = (const int*)d_in[2];
    p.feat_s = (const float*)d_in[3];
    p.src_s  = (const int*)d_in[4];
    p.dst_s  = (const int*)d_in[5];
    p.W0 = (const float*)d_in[6];  p.b0 = (const float*)d_in[7];
    p.W1 = (const float*)d_in[8];  p.b1 = (const float*)d_in[9];
    p.W2 = (const float*)d_in[10]; p.b2 = (const float*)d_in[11];
    p.Wr = (const float*)d_in[12]; p.br = (const float*)d_in[13];
    p.Wm1 = (const float*)d_in[14]; p.bm1 = (const float*)d_in[15];
    p.Wm2 = (const float*)d_in[16]; p.bm2 = (const float*)d_in[17];
    p.out = (float*)d_out;
    p.bar = bar; p.sums = sums; p.inv = inv; p.w1 = w1; p.w2 = w2; p.u3 = u3;
    p.fpart = fpart; p.fpart2 = fpart2; p.rep = rep;
    p.N = N; p.E = E; p.HN = HN; p.NBg = NBg;
    p.u0 = 1.0f / (float)N;

    const unsigned lds_bytes = (unsigned)(HN * sizeof(float));  // 50 KB
    fused_kernel<<<NBLK, 512, lds_bytes, stream>>>(p);
}

// Round 13
// 279.504 us; speedup vs baseline: 3.1840x; 3.0116x over previous
//
#include <hip/hip_runtime.h>
#include <math.h>

#define D 128
#define HQ 4        // node quarters
#define BB 64       // scan chunks per (g,h): grid = 2*HQ*BB = 512 blocks

// ---------------------------------------------------------------------------
// Collapsed linear GCN (math unchanged, absmax 0.0 since R0):
//   u0 = 1/N,  u_{k+1}[s] = sum_{e: src_e=s} inv_deg[dst_e] * u_k[dst_e]
//   mean(h3) = r@W0W1W2 + s2*(b0@W1W2) + s1*(b1@W2) + b2,  r = u3^T feat
// R9-R11 FAILED (fusion): coop launch rejected; __threadfence = per-block L2
// sweeps (808us); agent-scope bypass = 309MB uncached HBM at ~10x/byte
// (758us). MEASURED LESSON: kernel boundaries are the only cheap cross-XCD
// coherence. R12: optimize the R8 multi-kernel shape:
//   - scans 1024-thr x B=64: 32 waves/CU (max) + rep 38.4->25.6 MB/pass
//   - featsum atomically accumulates into fpart2 (kills fpart2 kernel+boundary)
//   - sums+fpart2 zeroed inside deg kernel (kills memset launch)
// ---------------------------------------------------------------------------

// scatter pass: rep[g][h][b][HN] partial sums.
//   deg pass:  tgt = dst arrays, w = null  -> +1 per edge (also zeroes zbase)
//   prop pass: tgt = src arrays, oth = dst, w -> + w[g*N + dst[e]] * scale
__global__ __launch_bounds__(1024, 8) void scan_scatter(
        const int* __restrict__ tgt_p, const int* __restrict__ oth_p,
        const int* __restrict__ tgt_s, const int* __restrict__ oth_s,
        const float* __restrict__ w, float* __restrict__ rep,
        float* __restrict__ zbase, int zcount,
        int E, int N, int HN, float scale) {
    const int b = blockIdx.x, h = blockIdx.y, g = blockIdx.z;
    const int* tgt = g ? tgt_s : tgt_p;
    const int* oth = g ? oth_s : oth_p;
    const float* wg = w ? (w + (size_t)g * N) : nullptr;

    if (zbase && b == 0 && h == 0 && g == 0)
        for (int i = threadIdx.x; i < zcount; i += 1024) zbase[i] = 0.f;

    extern __shared__ float lds[];  // HN floats (HN % 4 == 0)
    {
        float4 z = make_float4(0.f, 0.f, 0.f, 0.f);
        float4* l4 = (float4*)lds;
        for (int i = threadIdx.x; i < HN / 4; i += 1024) l4[i] = z;
    }
    __syncthreads();

    const int lo = h * HN;
    const int hi = min(lo + HN, N);
    const unsigned span = (unsigned)(hi - lo);
    int C = (E + BB - 1) / BB;
    C = (C + 7) & ~7;
    const int e0 = b * C;
    const int e1 = min(e0 + C, E);

    for (int e = e0 + (int)threadIdx.x * 8; e < e1; e += 1024 * 8) {
        if (e + 8 <= e1) {
            int4 ta = *(const int4*)(tgt + e);
            int4 tb = *(const int4*)(tgt + e + 4);
            int idx[8] = {ta.x, ta.y, ta.z, ta.w, tb.x, tb.y, tb.z, tb.w};
            bool hit[8];
            #pragma unroll
            for (int k = 0; k < 8; ++k) hit[k] = (unsigned)(idx[k] - lo) < span;
            if (wg) {
                int4 oa = *(const int4*)(oth + e);
                int4 ob = *(const int4*)(oth + e + 4);
                int od[8] = {oa.x, oa.y, oa.z, oa.w, ob.x, ob.y, ob.z, ob.w};
                float val[8];
                #pragma unroll
                for (int k = 0; k < 8; ++k) val[k] = hit[k] ? wg[od[k]] : 0.f;
                #pragma unroll
                for (int k = 0; k < 8; ++k)
                    if (hit[k]) atomicAdd(&lds[idx[k] - lo], val[k] * scale);
            } else {
                #pragma unroll
                for (int k = 0; k < 8; ++k)
                    if (hit[k]) atomicAdd(&lds[idx[k] - lo], 1.0f);
            }
        } else {
            for (int e2 = e; e2 < e1; ++e2) {
                int t = tgt[e2];
                if ((unsigned)(t - lo) < span) {
                    float v = wg ? wg[oth[e2]] * scale : 1.0f;
                    atomicAdd(&lds[t - lo], v);
                }
            }
        }
    }
    __syncthreads();

    float* dst = rep + (((size_t)g * HQ + h) * BB + b) * HN;
    float4* d4 = (float4*)dst;
    const float4* l4 = (const float4*)lds;
    for (int i = threadIdx.x; i < HN / 4; i += 1024) d4[i] = l4[i];
}

// 256 threads = 64 quads x 4 B-slices; each thread sums B/4 = 16 partials.
__global__ __launch_bounds__(256) void reduce_inv(
        const float* __restrict__ rep, float* __restrict__ inv,
        int N, int HN) {
    const int lane = threadIdx.x & 63;
    const int s = threadIdx.x >> 6;
    const int i = (blockIdx.x * 64 + lane) * 4;
    const int bps = BB >> 2;                  // 16
    float4 u = make_float4(0.f, 0.f, 0.f, 0.f);
    if (i < 2 * N) {
        int g = (i < N) ? 0 : 1;
        int n = i - g * N;
        int h = n / HN, l = n - h * HN;
        const float* base = rep + (((size_t)g * HQ + h) * BB + (size_t)s * bps) * HN + l;
        #pragma unroll 16
        for (int b = 0; b < bps; b++) {
            float4 v = *(const float4*)(base + (size_t)b * HN);
            u.x += v.x; u.y += v.y; u.z += v.z; u.w += v.w;
        }
    }
    __shared__ float4 sm[256];
    sm[threadIdx.x] = u;
    __syncthreads();
    if (s == 0 && i < 2 * N) {
        float4 a = sm[lane], b4 = sm[64 + lane], c = sm[128 + lane], d = sm[192 + lane];
        float4 r;
        r.x = 1.0f / fmaxf(a.x + b4.x + c.x + d.x, 1.0f);
        r.y = 1.0f / fmaxf(a.y + b4.y + c.y + d.y, 1.0f);
        r.z = 1.0f / fmaxf(a.z + b4.z + c.z + d.z, 1.0f);
        r.w = 1.0f / fmaxf(a.w + b4.w + c.w + d.w, 1.0f);
        *(float4*)(inv + i) = r;
    }
}

// u = sum_b rep; optional out_u, out_w = u*inv; optional per-graph sums
__global__ __launch_bounds__(256) void reduce_u(
        const float* __restrict__ rep, const float* __restrict__ inv,
        float* __restrict__ out_u, float* __restrict__ out_w,
        float* __restrict__ sums, int s_idx, int N, int HN) {
    const int lane = threadIdx.x & 63;
    const int s = threadIdx.x >> 6;
    const int i = (blockIdx.x * 64 + lane) * 4;
    const int bps = BB >> 2;                  // 16
    float4 u = make_float4(0.f, 0.f, 0.f, 0.f);
    if (i < 2 * N) {
        int g = (i < N) ? 0 : 1;
        int n = i - g * N;
        int h = n / HN, l = n - h * HN;
        const float* base = rep + (((size_t)g * HQ + h) * BB + (size_t)s * bps) * HN + l;
        #pragma unroll 16
        for (int b = 0; b < bps; b++) {
            float4 v = *(const float4*)(base + (size_t)b * HN);
            u.x += v.x; u.y += v.y; u.z += v.z; u.w += v.w;
        }
    }
    __shared__ float4 sm[256];
    __shared__ float s0[64], s1[64];
    sm[threadIdx.x] = u;
    __syncthreads();
    if (s == 0) {
        float tp = 0.f, ts = 0.f;
        if (i < 2 * N) {
            float4 a = sm[lane], b4 = sm[64 + lane], c = sm[128 + lane], d = sm[192 + lane];
            float4 uu;
            uu.x = a.x + b4.x + c.x + d.x;
            uu.y = a.y + b4.y + c.y + d.y;
            uu.z = a.z + b4.z + c.z + d.z;
            uu.w = a.w + b4.w + c.w + d.w;
            if (out_u) *(float4*)(out_u + i) = uu;
            if (out_w) {
                float4 iv = *(const float4*)(inv + i);
                *(float4*)(out_w + i) =
                    make_float4(uu.x * iv.x, uu.y * iv.y, uu.z * iv.z, uu.w * iv.w);
            }
            float t = uu.x + uu.y + uu.z + uu.w;
            if (i < N) tp = t; else ts = t;
        }
        s0[lane] = tp; s1[lane] = ts;
    }
    __syncthreads();
    if (sums) {
        for (int st = 32; st > 0; st >>= 1) {
            if ((int)threadIdx.x < st) {
                s0[threadIdx.x] += s0[threadIdx.x + st];
                s1[threadIdx.x] += s1[threadIdx.x + st];
            }
            __syncthreads();
        }
        if (threadIdx.x == 0) {
            if (s0[0] != 0.f) atomicAdd(&sums[0 * 2 + s_idx], s0[0]);
            if (s1[0] != 0.f) atomicAdd(&sums[1 * 2 + s_idx], s1[0]);
        }
    }
}

// featsum: per-block partial of u3^T feat, atomically accumulated into
// fpart2[g][blockIdx.x & 15][c]  (fpart2 pre-zeroed by deg kernel).
__global__ __launch_bounds__(256) void featsum_kernel(
        const float* __restrict__ feat_p, const float* __restrict__ feat_s,
        const float* __restrict__ u3, float* __restrict__ fpart2,
        int N, int rpb) {
    const int g = blockIdx.y;
    const float* feat = g ? feat_s : feat_p;
    const float* u = u3 + (size_t)g * N;
    const int col4 = threadIdx.x & 31;
    const int rgrp = threadIdx.x >> 5;   // 0..7
    const int r0 = blockIdx.x * rpb;
    const int r1 = min(r0 + rpb, N);

    const float4* f4 = (const float4*)feat;
    float4 acc = make_float4(0.f, 0.f, 0.f, 0.f);
    for (int n = r0 + rgrp * 4; n + 3 < r1; n += 32) {
        float4 uu = *(const float4*)(u + n);
        float4 v0 = f4[(size_t)n * 32 + col4];
        float4 v1 = f4[(size_t)(n + 1) * 32 + col4];
        float4 v2 = f4[(size_t)(n + 2) * 32 + col4];
        float4 v3 = f4[(size_t)(n + 3) * 32 + col4];
        acc.x += uu.x * v0.x + uu.y * v1.x + uu.z * v2.x + uu.w * v3.x;
        acc.y += uu.x * v0.y + uu.y * v1.y + uu.z * v2.y + uu.w * v3.y;
        acc.z += uu.x * v0.z + uu.y * v1.z + uu.z * v2.z + uu.w * v3.z;
        acc.w += uu.x * v0.w + uu.y * v1.w + uu.z * v2.w + uu.w * v3.w;
    }
    __shared__ float4 smem[256];
    smem[threadIdx.x] = acc;
    __syncthreads();
    if (rgrp == 0) {
        float4 t = smem[col4];
        #pragma unroll
        for (int k = 1; k < 8; k++) {
            float4 o = smem[k * 32 + col4];
            t.x += o.x; t.y += o.y; t.z += o.z; t.w += o.w;
        }
        float* dst = fpart2 + ((size_t)g * 16 + (blockIdx.x & 15)) * 128 + col4 * 4;
        atomicAdd(dst + 0, t.x);
        atomicAdd(dst + 1, t.y);
        atomicAdd(dst + 2, t.z);
        atomicAdd(dst + 3, t.w);
    }
}

// 512 threads: split-K matvecs. j = tid&127, h = tid>>7.
__global__ __launch_bounds__(512) void final_kernel(
        const float* __restrict__ fpart2,
        const float* __restrict__ sums,
        const float* __restrict__ W0, const float* __restrict__ b0,
        const float* __restrict__ W1, const float* __restrict__ b1,
        const float* __restrict__ W2, const float* __restrict__ b2,
        const float* __restrict__ Wr, const float* __restrict__ br,
        const float* __restrict__ Wm1, const float* __restrict__ bm1,
        const float* __restrict__ Wm2, const float* __restrict__ bm2,
        float* __restrict__ out) {
    __shared__ float x[128];
    __shared__ float part[4][128];
    __shared__ float rvec[256];
    __shared__ float Avec[128], Bvec[128];
    __shared__ float gv[256];
    const int tid = threadIdx.x;
    const int j = tid & 127;
    const int h = tid >> 7;

    auto mv128 = [&](const float* __restrict__ W, float* __restrict__ buf) {
        float p = 0.f;
        const float* Wp = W + (size_t)(h * 32) * 128 + j;
        #pragma unroll
        for (int i = 0; i < 32; ++i) p += buf[h * 32 + i] * Wp[(size_t)i * 128];
        part[h][j] = p;
        __syncthreads();
        if (h == 0) buf[j] = part[0][j] + part[1][j] + part[2][j] + part[3][j];
        __syncthreads();
    };

    if (tid < 256) {
        int g = tid >> 7;
        const float* fp = fpart2 + (size_t)g * 2048 + (tid & 127);
        float rv = 0.f;
        #pragma unroll
        for (int b = 0; b < 16; ++b) rv += fp[(size_t)b * 128];
        rvec[tid] = rv;
    }
    __syncthreads();

    if (tid < 128) x[tid] = b0[tid];
    __syncthreads();
    mv128(W1, x);
    mv128(W2, x);
    if (tid < 128) Avec[tid] = x[tid];
    __syncthreads();
    if (tid < 128) x[tid] = b1[tid];
    __syncthreads();
    mv128(W2, x);
    if (tid < 128) Bvec[tid] = x[tid];
    __syncthreads();

    for (int g = 0; g < 2; ++g) {
        const float s1 = sums[g * 2 + 0];
        const float s2 = sums[g * 2 + 1];
        if (tid < 128) x[tid] = rvec[g * 128 + tid];
        __syncthreads();
        mv128(W0, x);
        mv128(W1, x);
        mv128(W2, x);
        if (tid < 128) x[tid] += s2 * Avec[tid] + s1 * Bvec[tid] + b2[tid];
        __syncthreads();
        mv128(Wr, x);
        if (tid < 128) gv[g * 128 + tid] = 1.0f / (1.0f + expf(-(x[tid] + br[tid])));
        __syncthreads();
    }

    {
        float p = 0.f;
        const float* Wp = Wm1 + (size_t)(h * 64) * 128 + j;
        #pragma unroll
        for (int i = 0; i < 64; ++i) p += gv[h * 64 + i] * Wp[(size_t)i * 128];
        part[h][j] = p;
        __syncthreads();
        if (h == 0)
            part[0][j] = (part[0][j] + part[1][j] + part[2][j] + part[3][j] + bm1[j]) * Wm2[j];
        __syncthreads();
        if (tid < 64) part[0][tid] += part[0][tid + 64];
        __syncthreads();
        if (tid < 32) part[0][tid] += part[0][tid + 32];
        __syncthreads();
        if (tid < 16) part[0][tid] += part[0][tid + 16];
        __syncthreads();
        if (tid < 8) part[0][tid] += part[0][tid + 8];
        __syncthreads();
        if (tid < 4) part[0][tid] += part[0][tid + 4];
        __syncthreads();
        if (tid < 2) part[0][tid] += part[0][tid + 2];
        __syncthreads();
        if (tid == 0) out[0] = 1.0f / (1.0f + expf(-(part[0][0] + part[0][1] + bm2[0])));
    }
}

extern "C" void kernel_launch(void* const* d_in, const int* in_sizes, int n_in,
                              void* d_out, int out_size, void* d_ws, size_t ws_size,
                              hipStream_t stream) {
    const float* feat_p = (const float*)d_in[0];
    const int*   src_p  = (const int*)d_in[1];
    const int*   dst_p  = (const int*)d_in[2];
    const float* feat_s = (const float*)d_in[3];
    const int*   src_s  = (const int*)d_in[4];
    const int*   dst_s  = (const int*)d_in[5];
    const float* W0 = (const float*)d_in[6];
    const float* b0 = (const float*)d_in[7];
    const float* W1 = (const float*)d_in[8];
    const float* b1 = (const float*)d_in[9];
    const float* W2 = (const float*)d_in[10];
    const float* b2 = (const float*)d_in[11];
    const float* Wr = (const float*)d_in[12];
    const float* br = (const float*)d_in[13];
    const float* Wm1 = (const float*)d_in[14];
    const float* bm1 = (const float*)d_in[15];
    const float* Wm2 = (const float*)d_in[16];
    const float* bm2 = (const float*)d_in[17];
    float* out = (float*)d_out;

    const int N = in_sizes[0] / D;   // 50000
    const int E = in_sizes[1];       // 1600000
    const int N2 = 2 * N;

    int HN = (N + HQ - 1) / HQ;
    HN = (HN + 3) & ~3;              // 12500
    const int FB = 256;              // featsum blocks per graph
    const int rpb = (((N + FB - 1) / FB) + 3) & ~3;   // 196

    // ws (floats): sums[16] | fpart2[2*16*128] | inv[2N] | w1[2N] | w2[2N] |
    //              u3[2N] | rep[2*HQ*BB*HN]   (sums+fpart2 zeroed by deg kernel)
    float* ws     = (float*)d_ws;
    float* sums   = ws;
    float* fpart2 = ws + 16;
    float* inv    = fpart2 + 2 * 16 * 128;
    float* w1     = inv + N2;
    float* w2     = w1 + N2;
    float* u3     = w2 + N2;
    float* rep    = u3 + N2;

    const dim3 sgrid(BB, HQ, 2);     // 512 blocks x 1024 thr, 2/CU, 32 waves/CU
    const size_t lds_bytes = (size_t)HN * sizeof(float);  // 50 KB
    const int gQ = (N2 / 4 + 63) / 64;   // 391 reduce blocks
    const float u0 = 1.0f / (float)N;
    const int zcount = 16 + 2 * 16 * 128;

    // deg (also zeroes sums + fpart2)
    scan_scatter<<<sgrid, 1024, lds_bytes, stream>>>(dst_p, nullptr, dst_s, nullptr,
                                                     nullptr, rep, sums, zcount,
                                                     E, N, HN, 1.0f);
    reduce_inv<<<gQ, 256, 0, stream>>>(rep, inv, N, HN);

    scan_scatter<<<sgrid, 1024, lds_bytes, stream>>>(src_p, dst_p, src_s, dst_s,
                                                     inv, rep, nullptr, 0,
                                                     E, N, HN, u0);
    reduce_u<<<gQ, 256, 0, stream>>>(rep, inv, nullptr, w1, sums, 0, N, HN);

    scan_scatter<<<sgrid, 1024, lds_bytes, stream>>>(src_p, dst_p, src_s, dst_s,
                                                     w1, rep, nullptr, 0,
                                                     E, N, HN, 1.0f);
    reduce_u<<<gQ, 256, 0, stream>>>(rep, inv, nullptr, w2, sums, 1, N, HN);

    scan_scatter<<<sgrid, 1024, lds_bytes, stream>>>(src_p, dst_p, src_s, dst_s,
                                                     w2, rep, nullptr, 0,
                                                     E, N, HN, 1.0f);
    reduce_u<<<gQ, 256, 0, stream>>>(rep, inv, u3, nullptr, nullptr, 0, N, HN);

    featsum_kernel<<<dim3(FB, 2), 256, 0, stream>>>(feat_p, feat_s, u3, fpart2, N, rpb);

    final_kernel<<<1, 512, 0, stream>>>(fpart2, sums, W0, b0, W1, b1, W2, b2,
                                        Wr, br, Wm1, bm1, Wm2, bm2, out);
}